// Round 2
// baseline (128.899 us; speedup 1.0000x reference)
//
#include <hip/hip_runtime.h>
#include <hip/hip_bf16.h>

#define NROWS 65536
#define DIM   256
#define KC    512
#define ALPHA 0.05f

#define BM    64
#define NT    4                     // tiles per block
#define GRID  (NROWS / (BM * NT))   // 256 blocks -> 1 per CU (LDS-limited)
#define SROW  260                   // LDS row stride in dwords: 1040 B (16B-aligned, 4-bank row skew)

typedef __attribute__((ext_vector_type(8))) short bf16x8;
typedef __attribute__((ext_vector_type(4))) float f32x4;

static __device__ __forceinline__ unsigned short f2bf(float f) {
    union { __hip_bfloat16 h; unsigned short u; } c;
    c.h = __float2bfloat16(f);
    return c.u;
}
static __device__ __forceinline__ float bf2f(unsigned short u) {
    union { unsigned short u; __hip_bfloat16 h; } c;
    c.u = u;
    return __bfloat162float(c.h);
}

// Fragment-major center layout (verified in the 118.7us session): for chunk ch
// (64 centers), wave w, k-step kk, lane l = q*16+m reads center row
// ch*64+w*16+m, elems kk*32+q*8 .. +7 (16 B). uint4 index = ((ch*4+w)*8+kk)*64+l.
__global__ void prep_centers(const float* __restrict__ centers,
                             float* __restrict__ csqh,
                             uint4* __restrict__ cbf2,
                             float* __restrict__ out) {
    const int t = threadIdx.x;
    const int r = blockIdx.x * 8 + (t >> 5);  // center row
    const int e = t & 31;                     // 8-elem group within row
    const float4* cv = reinterpret_cast<const float4*>(centers);
    float4 v0 = cv[r * 64 + e * 2];
    float4 v1 = cv[r * 64 + e * 2 + 1];
    float s = v0.x * v0.x + v0.y * v0.y + v0.z * v0.z + v0.w * v0.w
            + v1.x * v1.x + v1.y * v1.y + v1.z * v1.z + v1.w * v1.w;
    unsigned short o[8];
    o[0] = f2bf(v0.x); o[1] = f2bf(v0.y); o[2] = f2bf(v0.z); o[3] = f2bf(v0.w);
    o[4] = f2bf(v1.x); o[5] = f2bf(v1.y); o[6] = f2bf(v1.z); o[7] = f2bf(v1.w);
    const int ch = r >> 6, w = (r >> 4) & 3, m = r & 15;
    const int kk = e >> 2, q = e & 3, l = q * 16 + m;
    cbf2[(((ch * 4 + w) * 8) + kk) * 64 + l] = *reinterpret_cast<uint4*>(o);
    #pragma unroll
    for (int off = 16; off; off >>= 1) s += __shfl_xor(s, off, 64);
    if (e == 0) csqh[r] = 0.5f * s;
    if (blockIdx.x == 0 && t == 0) out[0] = 0.f;  // separate dispatch -> ordered
}

// Persistent pipelined kernel: 4 tiles/block, fp32 A staged via global_load_lds
// into double-buffered LDS; DMA for tile t+2 interleaved 2-rows-per-chunk with
// the MFMA loop (counted-vmcnt pacing via in-order VMEM retirement).
__global__ __launch_bounds__(256, 1) void kmeans_main(
    const float* __restrict__ emb,
    const uint4* __restrict__ cbf2,
    const float* __restrict__ csqh_g,
    float* __restrict__ out) {
    __shared__ __align__(16) float fbuf[2][BM * SROW];  // 2 x 66560 B = 133120 B
    __shared__ float xsq_s[2][4][BM];                   // parity-buffered partials
    __shared__ float rowmax_s[2][4][BM];

    const int t = threadIdx.x;
    const int w = t >> 6;
    const int lane = t & 63;
    const int m = lane & 15;
    const int q = lane >> 4;
    const size_t block_row0 = (size_t)blockIdx.x * (BM * NT);

    // per-wave c^2/2 for this wave's 8 column slots (reused across all tiles)
    float c2h[8];
    #pragma unroll
    for (int ch = 0; ch < 8; ++ch) c2h[ch] = csqh_g[ch * 64 + w * 16 + m];

    const bf16x8* cb2 = reinterpret_cast<const bf16x8*>(cbf2);

    // One instr = one 1 KB row: uniform LDS base + lane*16B; per-lane global addr.
#define DMA_ROW(tt_, bb_, rr_)                                                   \
    do {                                                                         \
        const float* g_ = emb +                                                  \
            (block_row0 + (size_t)(tt_) * BM + (size_t)(rr_)) * DIM + (lane << 2); \
        __builtin_amdgcn_global_load_lds(                                        \
            (const __attribute__((address_space(1))) void*)g_,                   \
            (__attribute__((address_space(3))) void*)&fbuf[bb_][(rr_) * SROW],   \
            16, 0, 0);                                                           \
    } while (0)

    // ---- prologue: DMA tiles 0 and 1; wait tile 0 only (16 of 32 in flight) ----
    #pragma unroll
    for (int j = 0; j < 16; ++j) DMA_ROW(0, 0, w * 16 + j);
    #pragma unroll
    for (int j = 0; j < 16; ++j) DMA_ROW(1, 1, w * 16 + j);
    asm volatile("s_waitcnt vmcnt(16)\n\ts_barrier" ::: "memory");

    for (int tt = 0; tt < NT; ++tt) {
        const int p = tt & 1;
        const bool dma_on = (tt + 2 < NT);

        // ---- convert: LDS fp32 -> bf16 A fragments in regs (+ xsq partial) ----
        // SROW=260 => bank = (4m + 8q + 4h + e) % 32: conflict-free b128 reads.
        bf16x8 afr[4][8];
        float xacc[4] = {0.f, 0.f, 0.f, 0.f};
        #pragma unroll
        for (int rt = 0; rt < 4; ++rt) {
            const float* rp = &fbuf[p][(rt * 16 + m) * SROW + q * 8];
            #pragma unroll
            for (int kk = 0; kk < 8; ++kk) {
                f32x4 v0 = *reinterpret_cast<const f32x4*>(rp + kk * 32);
                f32x4 v1 = *reinterpret_cast<const f32x4*>(rp + kk * 32 + 4);
                unsigned short o[8];
                o[0] = f2bf(v0.x); o[1] = f2bf(v0.y); o[2] = f2bf(v0.z); o[3] = f2bf(v0.w);
                o[4] = f2bf(v1.x); o[5] = f2bf(v1.y); o[6] = f2bf(v1.z); o[7] = f2bf(v1.w);
                afr[rt][kk] = *reinterpret_cast<bf16x8*>(o);
                if ((kk >> 1) == w) {  // wave w owns kk-pair {2w,2w+1}: bf16-consistent x^2
                    #pragma unroll
                    for (int j = 0; j < 8; ++j) { float f = bf2f(o[j]); xacc[rt] += f * f; }
                }
            }
        }
        #pragma unroll
        for (int rt = 0; rt < 4; ++rt) {
            float s = xacc[rt];
            s += __shfl_xor(s, 16, 64);
            s += __shfl_xor(s, 32, 64);
            if (q == 0) xsq_s[p][w][rt * 16 + m] = s;
        }

        // ---- chunk-0 B preload BEFORE any tile t+2 DMA issue: its vmcnt wait
        //      then never blocks on the DMA stream (FIFO order). ----
        bf16x8 bcur[8];
        #pragma unroll
        for (int kk = 0; kk < 8; ++kk)
            bcur[kk] = cb2[((0 * 4 + w) * 8 + kk) * 64 + lane];

        // B1: all waves done reading fbuf[p]; raw barrier (NO vmcnt drain).
        asm volatile("s_waitcnt lgkmcnt(0)\n\ts_barrier" ::: "memory");

        float maxv[4][4];
        #pragma unroll
        for (int rt = 0; rt < 4; ++rt)
            #pragma unroll
            for (int rg = 0; rg < 4; ++rg) maxv[rt][rg] = -1e30f;

        #pragma unroll
        for (int ch = 0; ch < 8; ++ch) {
            // fire-and-forget: 2 rows of tile t+2 into the buffer we just freed.
            // In-order vmcnt retirement paces chunk ch's B-wait to ~2-row arrival.
            if (dma_on) {
                DMA_ROW(tt + 2, p, w * 16 + 2 * ch);
                DMA_ROW(tt + 2, p, w * 16 + 2 * ch + 1);
            }
            bf16x8 bnxt[8];
            if (ch < 7) {
                #pragma unroll
                for (int kk = 0; kk < 8; ++kk)
                    bnxt[kk] = cb2[(((ch + 1) * 4 + w) * 8 + kk) * 64 + lane];
            }
            const float ci = -c2h[ch];
            f32x4 acc[4];
            #pragma unroll
            for (int rt = 0; rt < 4; ++rt) acc[rt] = (f32x4){ci, ci, ci, ci};
            #pragma unroll
            for (int kk = 0; kk < 8; ++kk)
                #pragma unroll
                for (int rt = 0; rt < 4; ++rt)
                    acc[rt] = __builtin_amdgcn_mfma_f32_16x16x32_bf16(
                        afr[rt][kk], bcur[kk], acc[rt], 0, 0, 0);
            #pragma unroll
            for (int rt = 0; rt < 4; ++rt)
                #pragma unroll
                for (int rg = 0; rg < 4; ++rg)
                    maxv[rt][rg] = fmaxf(maxv[rt][rg], acc[rt][rg]);
            if (ch < 7) {
                #pragma unroll
                for (int kk = 0; kk < 8; ++kk) bcur[kk] = bnxt[kk];
            }
            // keep per-chunk issue order (DMA ∥ B-prefetch ∥ MFMA); prevents
            // the scheduler from hoisting all DMA to the loop head.
            __builtin_amdgcn_sched_barrier(0);
        }

        // ---- per-wave max over its 16 cols (xor over lane&15) ----
        #pragma unroll
        for (int rt = 0; rt < 4; ++rt)
            #pragma unroll
            for (int rg = 0; rg < 4; ++rg) {
                float v = maxv[rt][rg];
                v = fmaxf(v, __shfl_xor(v, 1, 64));
                v = fmaxf(v, __shfl_xor(v, 2, 64));
                v = fmaxf(v, __shfl_xor(v, 4, 64));
                v = fmaxf(v, __shfl_xor(v, 8, 64));
                if (m == 0) rowmax_s[p][w][rt * 16 + q * 4 + rg] = v;
            }
        // B2: rowmax/xsq visible; raw barrier again (t+2 DMA stays in flight).
        asm volatile("s_waitcnt lgkmcnt(0)\n\ts_barrier" ::: "memory");

        // ---- combine waves, d = sqrt(x2 - 2*max(cross - c2/2)), block sum ----
        if (t < 64) {
            float M = fmaxf(fmaxf(rowmax_s[p][0][t], rowmax_s[p][1][t]),
                            fmaxf(rowmax_s[p][2][t], rowmax_s[p][3][t]));
            float xs = xsq_s[p][0][t] + xsq_s[p][1][t]
                     + xsq_s[p][2][t] + xsq_s[p][3][t];
            float d = sqrtf(fmaxf(xs - 2.f * M, 0.f));
            #pragma unroll
            for (int off = 1; off < 64; off <<= 1) d += __shfl_xor(d, off, 64);
            if (t == 0) atomicAdd(out, d * (ALPHA / (float)NROWS));
        }
        // next tile reads fbuf[p^1] (its DMA forced-retired by this tile's
        // B-use waits, cross-wave ordered by B2) and writes xsq_s[p^1]/rowmax_s[p^1].
    }
    // safety: never reach s_endpgm with an outstanding LDS-DMA (cheap: the
    // tile-3 B-use waits already retired everything in normal scheduling).
    asm volatile("s_waitcnt vmcnt(0)" ::: "memory");
#undef DMA_ROW
}

extern "C" void kernel_launch(void* const* d_in, const int* in_sizes, int n_in,
                              void* d_out, int out_size, void* d_ws, size_t ws_size,
                              hipStream_t stream) {
    const float* emb     = (const float*)d_in[0];   // [65536, 256] fp32
    const float* centers = (const float*)d_in[1];   // [512, 256] fp32
    float* out = (float*)d_out;

    float* csqh = (float*)d_ws;                       // 512 * 4 B
    uint4* cbf2 = (uint4*)((char*)d_ws + 2048);       // 256 KB fragment-major bf16

    prep_centers<<<dim3(KC / 8), dim3(256), 0, stream>>>(centers, csqh, cbf2, out);
    kmeans_main<<<dim3(GRID), dim3(256), 0, stream>>>(emb, cbf2, csqh, out);
}